// Round 8
// baseline (2289.730 us; speedup 1.0000x reference)
//
#include <hip/hip_runtime.h>
#include <math.h>

#define NB 1000
#define NT 100
#define NI 264
#define NH 100
#define NO 264
#define NG 400          // 4*NH
#define KE 364          // NI + NH (fallback combined K)
#define DM 4            // decoder rows per block (250 blocks per decoder, 500 total)
#define NDB 250         // blocks per decoder
#define EDM 4           // encoder rows per block (250 blocks -> full GPU)
#define DTH 192         // decoder threads: 0-99 gate (4 cols), 128-191 fc (4-5 cols), rest idle
#define XM 16           // xp rows per block

__device__ __forceinline__ float sigm(float x){ return 1.f / (1.f + __expf(-x)); }
__device__ __forceinline__ float tanh_fast(float x){
    float e = __expf(-2.f * x);
    return 2.f / (1.f + e) - 1.f;
}

// param names must never collide with member tokens .x/.y/.z/.w
#define FMA4(acc, hv, wv) acc += hv.x*wv.x + hv.y*wv.y + hv.z*wv.z + hv.w*wv.w;

// 25-way repetition for enc_rec's register-resident Whh (kept from r5/r7).
#define W_LIST(OP) OP(0) OP(1) OP(2) OP(3) OP(4) OP(5) OP(6) OP(7) OP(8) OP(9) \
                   OP(10) OP(11) OP(12) OP(13) OP(14) OP(15) OP(16) OP(17) OP(18) OP(19) \
                   OP(20) OP(21) OP(22) OP(23) OP(24)

#define DECL_W(i)    float4 w##i = make_float4(0.f, 0.f, 0.f, 0.f);
#define LOADW_ENC(i) w##i = WhhT4[(i) * NG + n];

#define ROW4K(wv, kk) { float4 hq; \
    hq = ((const float4*)sh_h[0])[kk]; FMA4(a0, hq, wv) \
    hq = ((const float4*)sh_h[1])[kk]; FMA4(a1, hq, wv) \
    hq = ((const float4*)sh_h[2])[kk]; FMA4(a2, hq, wv) \
    hq = ((const float4*)sh_h[3])[kk]; FMA4(a3, hq, wv) }

#define ESTEP(i) ROW4K(w##i, i)

// ---------------- prep kernels ----------------

// generic k4-major transpose: out[(k4*N + n)*4 + j] = in[n*K + 4*k4 + j]
__global__ void prep_T4(const float* __restrict__ in, float* __restrict__ out, int N, int K)
{
    int idx = blockIdx.x * 256 + threadIdx.x;
    if (idx >= N * K) return;
    int j  = idx & 3;
    int n  = (idx >> 2) % N;
    int k  = (idx / (4 * N)) * 4 + j;
    out[idx] = in[n * K + k];
}

// fallback: combined [Wih | Whh] transposed k4-major (K = 364)
__global__ void prep_encT(const float* __restrict__ Wih, const float* __restrict__ Whh,
                          float* __restrict__ out)
{
    int idx = blockIdx.x * 256 + threadIdx.x;
    if (idx >= NG * KE) return;
    int j  = idx & 3;
    int n  = (idx >> 2) % NG;
    int k  = (idx / (4 * NG)) * 4 + j;
    out[idx] = (k < NI) ? Wih[n * NI + k] : Whh[n * NH + (k - NI)];
}

// WdecT4[(k4*NG+n)*4 + k&3] = Whh[n][k] + sum_o Wih[n][o]*fcW[o][k]  (feedback folded, transposed)
__global__ void prep_wdec(const float* __restrict__ Wih, const float* __restrict__ Whh,
                          const float* __restrict__ fcW, float* __restrict__ WdecT)
{
    int idx = blockIdx.x * 256 + threadIdx.x;
    if (idx >= NG * NH) return;
    int n = idx / NH, k = idx - n * NH;
    float acc = Whh[idx];
    const float* wr = Wih + (size_t)n * NI;
    for (int o = 0; o < NI; ++o) acc = fmaf(wr[o], fcW[o * NH + k], acc);
    WdecT[((k >> 2) * NG + n) * 4 + (k & 3)] = acc;
}

// b0 = bih+bhh ; bdec = b0 + Wih @ fcb ; bcat = enc bih+bhh ; zero loss
__global__ void prep_bias(const float* __restrict__ pb1, const float* __restrict__ pb2,
                          const float* __restrict__ pW,  const float* __restrict__ pfb,
                          const float* __restrict__ rb1, const float* __restrict__ rb2,
                          const float* __restrict__ rW,  const float* __restrict__ rfb,
                          const float* __restrict__ eb1, const float* __restrict__ eb2,
                          float* __restrict__ b0_p, float* __restrict__ bdec_p,
                          float* __restrict__ b0_r, float* __restrict__ bdec_r,
                          float* __restrict__ bcat, float* __restrict__ loss)
{
    int tid = blockIdx.x * 256 + threadIdx.x;
    if (tid < 2) loss[tid] = 0.f;
    if (tid < NG) bcat[tid] = eb1[tid] + eb2[tid];
    if (tid >= 2 * NG) return;
    int dd = tid / NG, n = tid - dd * NG;
    const float* b1 = dd ? rb1 : pb1;
    const float* b2 = dd ? rb2 : pb2;
    const float* W  = dd ? rW  : pW;
    const float* fb = dd ? rfb : pfb;
    float base = b1[n] + b2[n];
    float acc = base;
    const float* wr = W + (size_t)n * NI;
    for (int o = 0; o < NI; ++o) acc = fmaf(wr[o], fb[o], acc);
    if (dd){ b0_r[n] = base; bdec_r[n] = acc; }
    else   { b0_p[n] = base; bdec_p[n] = acc; }
}

// ---------------- XP: batched x-projection XP[bt][n] = src[bt] . Wih[n] ----------------

__global__ __launch_bounds__(512) void xp_kernel(const float* __restrict__ src,
                                                 const float4* __restrict__ WihT4,
                                                 float* __restrict__ xp)
{
    __shared__ float sh_x[XM * NI];   // 16.5 KB
    __shared__ float sh_o[XM * NG];   // 25.6 KB
    const int tid = threadIdx.x;
    const size_t bt0 = (size_t)blockIdx.x * XM;
    for (int i = tid; i < XM * NI; i += 512) sh_x[i] = src[bt0 * NI + i];
    __syncthreads();
    const bool act = tid < NG;
    const int n = act ? tid : 0;
    float a0=0,a1=0,a2=0,a3=0,a4=0,a5=0,a6=0,a7=0,
          a8=0,a9=0,a10=0,a11=0,a12=0,a13=0,a14=0,a15=0;
    if (act){
        #pragma unroll 3
        for (int k4 = 0; k4 < NI / 4; ++k4){
            float4 wq = WihT4[k4 * NG + n];
            float4 hq;
            #define XROW(r, acc) hq = ((const float4*)(sh_x + (r) * NI))[k4]; FMA4(acc, hq, wq)
            XROW(0,a0)  XROW(1,a1)  XROW(2,a2)  XROW(3,a3)
            XROW(4,a4)  XROW(5,a5)  XROW(6,a6)  XROW(7,a7)
            XROW(8,a8)  XROW(9,a9)  XROW(10,a10) XROW(11,a11)
            XROW(12,a12) XROW(13,a13) XROW(14,a14) XROW(15,a15)
            #undef XROW
        }
        sh_o[0*NG+n]=a0;   sh_o[1*NG+n]=a1;   sh_o[2*NG+n]=a2;   sh_o[3*NG+n]=a3;
        sh_o[4*NG+n]=a4;   sh_o[5*NG+n]=a5;   sh_o[6*NG+n]=a6;   sh_o[7*NG+n]=a7;
        sh_o[8*NG+n]=a8;   sh_o[9*NG+n]=a9;   sh_o[10*NG+n]=a10; sh_o[11*NG+n]=a11;
        sh_o[12*NG+n]=a12; sh_o[13*NG+n]=a13; sh_o[14*NG+n]=a14; sh_o[15*NG+n]=a15;
    }
    __syncthreads();
    for (int i = tid; i < XM * NG; i += 512) xp[bt0 * NG + i] = sh_o[i];
}

// ---------------- encoder recurrence (big-ws path): 4 rows/block, 250 blocks ----------------
// (unchanged from round 7 — ran clean; one lever per round)

__global__ __launch_bounds__(512) __attribute__((amdgpu_waves_per_eu(2, 2)))
void enc_rec(const float* __restrict__ xp,
             const float4* __restrict__ WhhT4,
             const float* __restrict__ bcat,
             float* __restrict__ h_out, float* __restrict__ c_out)
{
    __shared__ float sh_h[EDM][104];
    __shared__ float sh_g[NG][EDM + 1];
    const int tid = threadIdx.x;
    const int b0  = blockIdx.x * EDM;
    const bool act = tid < NG;
    const int n  = act ? tid : 0;
    const int mc = n / NH, jc = n % NH;
    float bias = act ? bcat[n] : 0.f;
    float c0 = 0.f;

    W_LIST(DECL_W)
    if (act){
        W_LIST(LOADW_ENC)
        sh_h[mc][jc] = 0.f;
    }
    __syncthreads();

    for (int t = 0; t < NT; ++t){
        if (act){
            const float* xr = xp + ((size_t)b0 * NT + t) * NG + n;
            float a0 = bias + xr[0 * NT * NG];
            float a1 = bias + xr[1 * NT * NG];
            float a2 = bias + xr[2 * NT * NG];
            float a3 = bias + xr[3 * NT * NG];
            W_LIST(ESTEP)
            sh_g[n][0]=a0; sh_g[n][1]=a1; sh_g[n][2]=a2; sh_g[n][3]=a3;
        }
        __syncthreads();
        if (act){
            float ai = sh_g[jc][mc], af = sh_g[NH + jc][mc];
            float ag = sh_g[2*NH + jc][mc], ao = sh_g[3*NH + jc][mc];
            float ii = sigm(ai), ff = sigm(af), gg = tanh_fast(ag), oo = sigm(ao);
            c0 = ff * c0 + ii * gg;
            sh_h[mc][jc] = oo * tanh_fast(c0);
        }
        __syncthreads();
    }
    if (act){
        h_out[(size_t)(b0 + mc) * NH + jc] = sh_h[mc][jc];
        c_out[(size_t)(b0 + mc) * NH + jc] = c0;
    }
}

// ---------------- encoder (fallback, small ws): stream combined WencT4, 4 rows/block ----------------

__global__ __launch_bounds__(512) void enc_stream(const float* __restrict__ src,
                                                  const float4* __restrict__ WencT4,
                                                  const float* __restrict__ bcat,
                                                  float* __restrict__ h_out, float* __restrict__ c_out)
{
    __shared__ float sh_xh[4][368];   // [0,264)=x, [264,364)=h
    __shared__ float sh_g[NG][5];
    const int tid = threadIdx.x;
    const int m0  = blockIdx.x * 4;
    const bool act = tid < NG;
    const int n  = act ? tid : 0;
    const int mc = n / NH, jc = n % NH;
    float bias = act ? bcat[n] : 0.f;
    float c_reg = 0.f, h_new = 0.f;
    if (act) sh_xh[mc][NI + jc] = 0.f;
    const float* s0 = src + (size_t)m0 * NT * NI;

    for (int t = 0; t < NT; ++t){
        for (int i = tid; i < 4 * NI; i += 512){
            int r = i / NI, k = i - r * NI;
            sh_xh[r][k] = s0[(size_t)r * NT * NI + (size_t)t * NI + k];
        }
        __syncthreads();
        if (act){
            float a0 = bias, a1 = bias, a2 = bias, a3 = bias;
            #pragma unroll 7
            for (int k4 = 0; k4 < KE / 4; ++k4){
                float4 wq = WencT4[k4 * NG + n];
                float4 hq;
                hq = ((const float4*)sh_xh[0])[k4]; FMA4(a0, hq, wq)
                hq = ((const float4*)sh_xh[1])[k4]; FMA4(a1, hq, wq)
                hq = ((const float4*)sh_xh[2])[k4]; FMA4(a2, hq, wq)
                hq = ((const float4*)sh_xh[3])[k4]; FMA4(a3, hq, wq)
            }
            sh_g[n][0]=a0; sh_g[n][1]=a1; sh_g[n][2]=a2; sh_g[n][3]=a3;
        }
        __syncthreads();
        if (act){
            float ai = sh_g[jc][mc], af = sh_g[NH + jc][mc];
            float ag = sh_g[2*NH + jc][mc], ao = sh_g[3*NH + jc][mc];
            float ii = sigm(ai), ff = sigm(af), gg = tanh_fast(ag), oo = sigm(ao);
            c_reg = ff * c_reg + ii * gg;
            h_new = oo * tanh_fast(c_reg);
            sh_xh[mc][NI + jc] = h_new;
        }
        __syncthreads();
    }
    if (act){
        h_out[(size_t)(m0 + mc) * NH + jc] = h_new;
        c_out[(size_t)(m0 + mc) * NH + jc] = c_reg;
    }
}

// ---------------- decoder: 4 columns per thread (C=4) ----------------
// r7 post-mortem: decoder is ISSUE-throughput bound (LDS ~12cyc/ds_read_b128 + VALU), both
// pipes per-CU shared -> occupancy doesn't help; reduce instructions instead. Each H-read
// from LDS now feeds 4 weight columns: ds insts/step 1038 -> ~300, addressing amortized 4x.
// gate: tid 0-99, cols n, n+100, n+200, n+300 (accumulation order per col unchanged ->
// bit-identical recurrence). fc: tid 128-191, cols o+64j j=0..3, lanes o<8 add col 256+o.
// Activation: tid 0-99 own all 4 rows (c0..c3).

__global__ __launch_bounds__(DTH) void decoder_kernel(
    const float* __restrict__ h_enc, const float* __restrict__ c_enc,
    const float4* __restrict__ WhhT_p, const float4* __restrict__ WdecT_p,
    const float* __restrict__ b0_p,  const float* __restrict__ bdec_p,
    const float4* __restrict__ fcWT_p, const float* __restrict__ fcb_p,
    const float* __restrict__ trg,
    const float4* __restrict__ WhhT_r, const float4* __restrict__ WdecT_r,
    const float* __restrict__ b0_r,  const float* __restrict__ bdec_r,
    const float4* __restrict__ fcWT_r, const float* __restrict__ fcb_r,
    const float* __restrict__ src,
    float* __restrict__ loss)
{
    __shared__ float sh_h[DM][104];
    __shared__ float sh_g[NG][DM + 1];
    __shared__ float sh_red[3];
    const int tid = threadIdx.x;
    const int d   = (blockIdx.x >= NDB) ? 1 : 0;
    const int m0  = (blockIdx.x - d * NDB) * DM;
    const float4* WhhT  = d ? WhhT_r  : WhhT_p;
    const float4* WdecT = d ? WdecT_r : WdecT_p;
    const float*  b0    = d ? b0_r    : b0_p;
    const float*  bdec  = d ? bdec_r  : bdec_p;
    const float4* fcWT  = d ? fcWT_r  : fcWT_p;
    const float*  fcb   = d ? fcb_r   : fcb_p;
    const float*  tgt   = d ? src     : trg;

    const bool gate = tid < NH;                       // 100 threads x 4 cols
    const bool fc   = (tid >= 128) && (tid < 192);    // 64 threads x 4 (+1) cols
    const int n  = gate ? tid : 0;
    const int o  = fc ? tid - 128 : 0;
    const bool fcx = fc && (o < 8);                   // 5th column owners (cols 256..263)

    float bz0=0,bz1=0,bz2=0,bz3=0, bd0=0,bd1=0,bd2=0,bd3=0;
    float fb0=0,fb1=0,fb2=0,fb3=0,fb4=0;
    if (gate){
        bz0=b0[n];        bz1=b0[n+NH];     bz2=b0[n+2*NH];   bz3=b0[n+3*NH];
        bd0=bdec[n];      bd1=bdec[n+NH];   bd2=bdec[n+2*NH]; bd3=bdec[n+3*NH];
    } else if (fc){
        fb0=fcb[o]; fb1=fcb[o+64]; fb2=fcb[o+128]; fb3=fcb[o+192];
        if (fcx) fb4=fcb[o+256];
    }

    float c0=0.f, c1=0.f, c2=0.f, c3=0.f;
    if (gate){
        c0 = c_enc[(size_t)(m0+0)*NH + n];
        c1 = c_enc[(size_t)(m0+1)*NH + n];
        c2 = c_enc[(size_t)(m0+2)*NH + n];
        c3 = c_enc[(size_t)(m0+3)*NH + n];
        sh_h[0][n] = h_enc[(size_t)(m0+0)*NH + n];
        sh_h[1][n] = h_enc[(size_t)(m0+1)*NH + n];
        sh_h[2][n] = h_enc[(size_t)(m0+2)*NH + n];
        sh_h[3][n] = h_enc[(size_t)(m0+3)*NH + n];
    }
    float loss_acc = 0.f;
    __syncthreads();

    for (int k = 0; k <= NT; ++k){
        if (gate && k < NT){
            const float4* WT = (k == 0) ? WhhT : WdecT;   // step 0: x=0 -> plain Whh
            float biasA = k ? bd0 : bz0, biasB = k ? bd1 : bz1;
            float biasC = k ? bd2 : bz2, biasD = k ? bd3 : bz3;
            float A0=biasA,A1=biasA,A2=biasA,A3=biasA;
            float B0=biasB,B1=biasB,B2=biasB,B3=biasB;
            float C0=biasC,C1=biasC,C2=biasC,C3=biasC;
            float D0=biasD,D1=biasD,D2=biasD,D3=biasD;
            #pragma unroll 5
            for (int k4 = 0; k4 < NH / 4; ++k4){
                float4 wa = WT[k4 * NG + n];
                float4 wb = WT[k4 * NG + n + NH];
                float4 wc = WT[k4 * NG + n + 2*NH];
                float4 wd = WT[k4 * NG + n + 3*NH];
                float4 h0q = ((const float4*)sh_h[0])[k4];
                float4 h1q = ((const float4*)sh_h[1])[k4];
                float4 h2q = ((const float4*)sh_h[2])[k4];
                float4 h3q = ((const float4*)sh_h[3])[k4];
                FMA4(A0,h0q,wa) FMA4(A1,h1q,wa) FMA4(A2,h2q,wa) FMA4(A3,h3q,wa)
                FMA4(B0,h0q,wb) FMA4(B1,h1q,wb) FMA4(B2,h2q,wb) FMA4(B3,h3q,wb)
                FMA4(C0,h0q,wc) FMA4(C1,h1q,wc) FMA4(C2,h2q,wc) FMA4(C3,h3q,wc)
                FMA4(D0,h0q,wd) FMA4(D1,h1q,wd) FMA4(D2,h2q,wd) FMA4(D3,h3q,wd)
            }
            sh_g[n][0]=A0;        sh_g[n][1]=A1;        sh_g[n][2]=A2;        sh_g[n][3]=A3;
            sh_g[n+NH][0]=B0;     sh_g[n+NH][1]=B1;     sh_g[n+NH][2]=B2;     sh_g[n+NH][3]=B3;
            sh_g[n+2*NH][0]=C0;   sh_g[n+2*NH][1]=C1;   sh_g[n+2*NH][2]=C2;   sh_g[n+2*NH][3]=C3;
            sh_g[n+3*NH][0]=D0;   sh_g[n+3*NH][1]=D1;   sh_g[n+3*NH][2]=D2;   sh_g[n+3*NH][3]=D3;
        } else if (fc && k >= 1){
            float P0=fb0,P1=fb0,P2=fb0,P3=fb0;
            float Q0=fb1,Q1=fb1,Q2=fb1,Q3=fb1;
            float R0=fb2,R1=fb2,R2=fb2,R3=fb2;
            float S0=fb3,S1=fb3,S2=fb3,S3=fb3;
            float T0=fb4,T1=fb4,T2=fb4,T3=fb4;
            #pragma unroll 5
            for (int k4 = 0; k4 < NH / 4; ++k4){
                float4 wa = fcWT[k4 * NO + o];
                float4 wb = fcWT[k4 * NO + o + 64];
                float4 wc = fcWT[k4 * NO + o + 128];
                float4 wd = fcWT[k4 * NO + o + 192];
                float4 h0q = ((const float4*)sh_h[0])[k4];
                float4 h1q = ((const float4*)sh_h[1])[k4];
                float4 h2q = ((const float4*)sh_h[2])[k4];
                float4 h3q = ((const float4*)sh_h[3])[k4];
                FMA4(P0,h0q,wa) FMA4(P1,h1q,wa) FMA4(P2,h2q,wa) FMA4(P3,h3q,wa)
                FMA4(Q0,h0q,wb) FMA4(Q1,h1q,wb) FMA4(Q2,h2q,wb) FMA4(Q3,h3q,wb)
                FMA4(R0,h0q,wc) FMA4(R1,h1q,wc) FMA4(R2,h2q,wc) FMA4(R3,h3q,wc)
                FMA4(S0,h0q,wd) FMA4(S1,h1q,wd) FMA4(S2,h2q,wd) FMA4(S3,h3q,wd)
                if (fcx){
                    float4 we = fcWT[k4 * NO + o + 256];
                    FMA4(T0,h0q,we) FMA4(T1,h1q,we) FMA4(T2,h2q,we) FMA4(T3,h3q,we)
                }
            }
            const int ti = d ? (NT - k) : (k - 1);   // pred index k-1, reversed for recon
            const float* tg = tgt + (size_t)m0 * NT * NI + (size_t)ti * NI;
            float df;
            df = P0 - tg[0*NT*NI + o];       loss_acc += df * df;
            df = P1 - tg[1*NT*NI + o];       loss_acc += df * df;
            df = P2 - tg[2*NT*NI + o];       loss_acc += df * df;
            df = P3 - tg[3*NT*NI + o];       loss_acc += df * df;
            df = Q0 - tg[0*NT*NI + o + 64];  loss_acc += df * df;
            df = Q1 - tg[1*NT*NI + o + 64];  loss_acc += df * df;
            df = Q2 - tg[2*NT*NI + o + 64];  loss_acc += df * df;
            df = Q3 - tg[3*NT*NI + o + 64];  loss_acc += df * df;
            df = R0 - tg[0*NT*NI + o + 128]; loss_acc += df * df;
            df = R1 - tg[1*NT*NI + o + 128]; loss_acc += df * df;
            df = R2 - tg[2*NT*NI + o + 128]; loss_acc += df * df;
            df = R3 - tg[3*NT*NI + o + 128]; loss_acc += df * df;
            df = S0 - tg[0*NT*NI + o + 192]; loss_acc += df * df;
            df = S1 - tg[1*NT*NI + o + 192]; loss_acc += df * df;
            df = S2 - tg[2*NT*NI + o + 192]; loss_acc += df * df;
            df = S3 - tg[3*NT*NI + o + 192]; loss_acc += df * df;
            if (fcx){
                df = T0 - tg[0*NT*NI + o + 256]; loss_acc += df * df;
                df = T1 - tg[1*NT*NI + o + 256]; loss_acc += df * df;
                df = T2 - tg[2*NT*NI + o + 256]; loss_acc += df * df;
                df = T3 - tg[3*NT*NI + o + 256]; loss_acc += df * df;
            }
        }
        __syncthreads();
        if (gate && k < NT){
            #define ACT(r, cc) { \
                float ai = sh_g[n][r], af = sh_g[NH + n][r]; \
                float ag = sh_g[2*NH + n][r], ao = sh_g[3*NH + n][r]; \
                float ii = sigm(ai), ff = sigm(af), gg = tanh_fast(ag), oo = sigm(ao); \
                cc = ff * cc + ii * gg; \
                sh_h[r][n] = oo * tanh_fast(cc); }
            ACT(0, c0) ACT(1, c1) ACT(2, c2) ACT(3, c3)
            #undef ACT
        }
        __syncthreads();
    }

    for (int off = 32; off > 0; off >>= 1) loss_acc += __shfl_down(loss_acc, off);
    if ((tid & 63) == 0) sh_red[tid >> 6] = loss_acc;
    __syncthreads();
    if (tid == 0){
        float s = sh_red[0] + sh_red[1] + sh_red[2];
        atomicAdd(&loss[d], s);
    }
}

__global__ void finalize_kernel(const float* __restrict__ loss, float* __restrict__ out){
    if (threadIdx.x == 0){
        const float inv = 1.f / 26400000.f;   // B*T*O
        out[0] = loss[1] * inv;   // reconstruct_loss
        out[1] = loss[0] * inv;   // predict_loss
    }
}

extern "C" void kernel_launch(void* const* d_in, const int* in_sizes, int n_in,
                              void* d_out, int out_size, void* d_ws, size_t ws_size,
                              hipStream_t stream)
{
    const float* src  = (const float*)d_in[0];
    const float* trg  = (const float*)d_in[1];
    const float* eWih = (const float*)d_in[2];
    const float* eWhh = (const float*)d_in[3];
    const float* ebih = (const float*)d_in[4];
    const float* ebhh = (const float*)d_in[5];
    const float* pWih = (const float*)d_in[6];
    const float* pWhh = (const float*)d_in[7];
    const float* pbih = (const float*)d_in[8];
    const float* pbhh = (const float*)d_in[9];
    const float* pfcW = (const float*)d_in[10];
    const float* pfcb = (const float*)d_in[11];
    const float* rWih = (const float*)d_in[12];
    const float* rWhh = (const float*)d_in[13];
    const float* rbih = (const float*)d_in[14];
    const float* rbhh = (const float*)d_in[15];
    const float* rfcW = (const float*)d_in[16];
    const float* rfcb = (const float*)d_in[17];

    float* w       = (float*)d_ws;
    float* WihT4e  = w;                 // 105600
    float* WencT4  = w + 105600;        // 145600 (fallback)
    float* WhhT4e  = w + 251200;        // 40000
    float* WdT_p   = w + 291200;        // 40000
    float* WdT_r   = w + 331200;        // 40000
    float* WhT_p   = w + 371200;        // 40000
    float* WhT_r   = w + 411200;        // 40000
    float* fcT_p   = w + 451200;        // 26400
    float* fcT_r   = w + 477600;        // 26400
    float* b0_p    = w + 504000;        // 400
    float* bdec_p  = w + 504400;        // 400
    float* b0_r    = w + 504800;        // 400
    float* bdec_r  = w + 505200;        // 400
    float* bcat    = w + 505600;        // 400
    float* h_enc   = w + 506000;        // 100000
    float* c_enc   = w + 606000;        // 100000
    float* loss    = w + 706000;        // 2
    float* XP      = w + 706016;        // 40,000,000 (big path only)
    const bool big = ws_size >= (size_t)(706016 + 40000000) * 4;

    const int TB = 256;
    if (big){
        prep_T4<<<(NG*NI + TB-1)/TB, TB, 0, stream>>>(eWih, WihT4e, NG, NI);
        prep_T4<<<(NG*NH + TB-1)/TB, TB, 0, stream>>>(eWhh, WhhT4e, NG, NH);
    } else {
        prep_encT<<<(NG*KE + TB-1)/TB, TB, 0, stream>>>(eWih, eWhh, WencT4);
    }
    prep_T4<<<(NG*NH + TB-1)/TB, TB, 0, stream>>>(pWhh, WhT_p, NG, NH);
    prep_T4<<<(NG*NH + TB-1)/TB, TB, 0, stream>>>(rWhh, WhT_r, NG, NH);
    prep_T4<<<(NO*NH + TB-1)/TB, TB, 0, stream>>>(pfcW, fcT_p, NO, NH);
    prep_T4<<<(NO*NH + TB-1)/TB, TB, 0, stream>>>(rfcW, fcT_r, NO, NH);
    prep_wdec<<<(NG*NH + TB-1)/TB, TB, 0, stream>>>(pWih, pWhh, pfcW, WdT_p);
    prep_wdec<<<(NG*NH + TB-1)/TB, TB, 0, stream>>>(rWih, rWhh, rfcW, WdT_r);
    prep_bias<<<4, TB, 0, stream>>>(pbih, pbhh, pWih, pfcb, rbih, rbhh, rWih, rfcb,
                                    ebih, ebhh, b0_p, bdec_p, b0_r, bdec_r, bcat, loss);

    if (big){
        xp_kernel<<<(NB*NT)/XM, 512, 0, stream>>>(src, (const float4*)WihT4e, XP);
        enc_rec<<<NB/EDM, 512, 0, stream>>>(XP, (const float4*)WhhT4e, bcat, h_enc, c_enc);
    } else {
        enc_stream<<<NB/4, 512, 0, stream>>>(src, (const float4*)WencT4, bcat, h_enc, c_enc);
    }
    decoder_kernel<<<2 * NDB, DTH, 0, stream>>>(h_enc, c_enc,
        (const float4*)WhT_p, (const float4*)WdT_p, b0_p, bdec_p, (const float4*)fcT_p, pfcb, trg,
        (const float4*)WhT_r, (const float4*)WdT_r, b0_r, bdec_r, (const float4*)fcT_r, rfcb, src,
        loss);
    finalize_kernel<<<1, 64, 0, stream>>>(loss, (float*)d_out);
}

// Round 9
// 2236.230 us; speedup vs baseline: 1.0239x; 1.0239x over previous
//
#include <hip/hip_runtime.h>
#include <math.h>

#define NB 1000
#define NT 100
#define NI 264
#define NH 100
#define NO 264
#define NG 400          // 4*NH
#define KE 364          // NI + NH (fallback combined K)
#define DM 4            // decoder rows per block (250 blocks per decoder, 500 total)
#define NDB 250         // blocks per decoder
#define EDM 4           // encoder rows per block (250 blocks -> full GPU)
#define DTH 384         // decoder threads: K-split x2 layout (see decoder comment)
#define XM 16           // xp rows per block

__device__ __forceinline__ float sigm(float x){ return 1.f / (1.f + __expf(-x)); }
__device__ __forceinline__ float tanh_fast(float x){
    float e = __expf(-2.f * x);
    return 2.f / (1.f + e) - 1.f;
}

// param names must never collide with member tokens .x/.y/.z/.w
#define FMA4(acc, hv, wv) acc += hv.x*wv.x + hv.y*wv.y + hv.z*wv.z + hv.w*wv.w;

// 25-way repetition for enc_rec's register-resident Whh (kept from r5/r7).
#define W_LIST(OP) OP(0) OP(1) OP(2) OP(3) OP(4) OP(5) OP(6) OP(7) OP(8) OP(9) \
                   OP(10) OP(11) OP(12) OP(13) OP(14) OP(15) OP(16) OP(17) OP(18) OP(19) \
                   OP(20) OP(21) OP(22) OP(23) OP(24)

#define DECL_W(i)    float4 w##i = make_float4(0.f, 0.f, 0.f, 0.f);
#define LOADW_ENC(i) w##i = WhhT4[(i) * NG + n];

#define ROW4K(wv, kk) { float4 hq; \
    hq = ((const float4*)sh_h[0])[kk]; FMA4(a0, hq, wv) \
    hq = ((const float4*)sh_h[1])[kk]; FMA4(a1, hq, wv) \
    hq = ((const float4*)sh_h[2])[kk]; FMA4(a2, hq, wv) \
    hq = ((const float4*)sh_h[3])[kk]; FMA4(a3, hq, wv) }

#define ESTEP(i) ROW4K(w##i, i)

// ---------------- prep kernels ----------------

// generic k4-major transpose: out[(k4*N + n)*4 + j] = in[n*K + 4*k4 + j]
__global__ void prep_T4(const float* __restrict__ in, float* __restrict__ out, int N, int K)
{
    int idx = blockIdx.x * 256 + threadIdx.x;
    if (idx >= N * K) return;
    int j  = idx & 3;
    int n  = (idx >> 2) % N;
    int k  = (idx / (4 * N)) * 4 + j;
    out[idx] = in[n * K + k];
}

// fallback: combined [Wih | Whh] transposed k4-major (K = 364)
__global__ void prep_encT(const float* __restrict__ Wih, const float* __restrict__ Whh,
                          float* __restrict__ out)
{
    int idx = blockIdx.x * 256 + threadIdx.x;
    if (idx >= NG * KE) return;
    int j  = idx & 3;
    int n  = (idx >> 2) % NG;
    int k  = (idx / (4 * NG)) * 4 + j;
    out[idx] = (k < NI) ? Wih[n * NI + k] : Whh[n * NH + (k - NI)];
}

// WdecT4[(k4*NG+n)*4 + k&3] = Whh[n][k] + sum_o Wih[n][o]*fcW[o][k]  (feedback folded, transposed)
__global__ void prep_wdec(const float* __restrict__ Wih, const float* __restrict__ Whh,
                          const float* __restrict__ fcW, float* __restrict__ WdecT)
{
    int idx = blockIdx.x * 256 + threadIdx.x;
    if (idx >= NG * NH) return;
    int n = idx / NH, k = idx - n * NH;
    float acc = Whh[idx];
    const float* wr = Wih + (size_t)n * NI;
    for (int o = 0; o < NI; ++o) acc = fmaf(wr[o], fcW[o * NH + k], acc);
    WdecT[((k >> 2) * NG + n) * 4 + (k & 3)] = acc;
}

// b0 = bih+bhh ; bdec = b0 + Wih @ fcb ; bcat = enc bih+bhh ; zero loss
__global__ void prep_bias(const float* __restrict__ pb1, const float* __restrict__ pb2,
                          const float* __restrict__ pW,  const float* __restrict__ pfb,
                          const float* __restrict__ rb1, const float* __restrict__ rb2,
                          const float* __restrict__ rW,  const float* __restrict__ rfb,
                          const float* __restrict__ eb1, const float* __restrict__ eb2,
                          float* __restrict__ b0_p, float* __restrict__ bdec_p,
                          float* __restrict__ b0_r, float* __restrict__ bdec_r,
                          float* __restrict__ bcat, float* __restrict__ loss)
{
    int tid = blockIdx.x * 256 + threadIdx.x;
    if (tid < 2) loss[tid] = 0.f;
    if (tid < NG) bcat[tid] = eb1[tid] + eb2[tid];
    if (tid >= 2 * NG) return;
    int dd = tid / NG, n = tid - dd * NG;
    const float* b1 = dd ? rb1 : pb1;
    const float* b2 = dd ? rb2 : pb2;
    const float* W  = dd ? rW  : pW;
    const float* fb = dd ? rfb : pfb;
    float base = b1[n] + b2[n];
    float acc = base;
    const float* wr = W + (size_t)n * NI;
    for (int o = 0; o < NI; ++o) acc = fmaf(wr[o], fb[o], acc);
    if (dd){ b0_r[n] = base; bdec_r[n] = acc; }
    else   { b0_p[n] = base; bdec_p[n] = acc; }
}

// ---------------- XP: batched x-projection XP[bt][n] = src[bt] . Wih[n] ----------------

__global__ __launch_bounds__(512) void xp_kernel(const float* __restrict__ src,
                                                 const float4* __restrict__ WihT4,
                                                 float* __restrict__ xp)
{
    __shared__ float sh_x[XM * NI];   // 16.5 KB
    __shared__ float sh_o[XM * NG];   // 25.6 KB
    const int tid = threadIdx.x;
    const size_t bt0 = (size_t)blockIdx.x * XM;
    for (int i = tid; i < XM * NI; i += 512) sh_x[i] = src[bt0 * NI + i];
    __syncthreads();
    const bool act = tid < NG;
    const int n = act ? tid : 0;
    float a0=0,a1=0,a2=0,a3=0,a4=0,a5=0,a6=0,a7=0,
          a8=0,a9=0,a10=0,a11=0,a12=0,a13=0,a14=0,a15=0;
    if (act){
        #pragma unroll 3
        for (int k4 = 0; k4 < NI / 4; ++k4){
            float4 wq = WihT4[k4 * NG + n];
            float4 hq;
            #define XROW(r, acc) hq = ((const float4*)(sh_x + (r) * NI))[k4]; FMA4(acc, hq, wq)
            XROW(0,a0)  XROW(1,a1)  XROW(2,a2)  XROW(3,a3)
            XROW(4,a4)  XROW(5,a5)  XROW(6,a6)  XROW(7,a7)
            XROW(8,a8)  XROW(9,a9)  XROW(10,a10) XROW(11,a11)
            XROW(12,a12) XROW(13,a13) XROW(14,a14) XROW(15,a15)
            #undef XROW
        }
        sh_o[0*NG+n]=a0;   sh_o[1*NG+n]=a1;   sh_o[2*NG+n]=a2;   sh_o[3*NG+n]=a3;
        sh_o[4*NG+n]=a4;   sh_o[5*NG+n]=a5;   sh_o[6*NG+n]=a6;   sh_o[7*NG+n]=a7;
        sh_o[8*NG+n]=a8;   sh_o[9*NG+n]=a9;   sh_o[10*NG+n]=a10; sh_o[11*NG+n]=a11;
        sh_o[12*NG+n]=a12; sh_o[13*NG+n]=a13; sh_o[14*NG+n]=a14; sh_o[15*NG+n]=a15;
    }
    __syncthreads();
    for (int i = tid; i < XM * NG; i += 512) xp[bt0 * NG + i] = sh_o[i];
}

// ---------------- encoder recurrence (big-ws path): 4 rows/block, 250 blocks ----------------
// (unchanged from rounds 7/8 — ran clean; one lever per round)

__global__ __launch_bounds__(512) __attribute__((amdgpu_waves_per_eu(2, 2)))
void enc_rec(const float* __restrict__ xp,
             const float4* __restrict__ WhhT4,
             const float* __restrict__ bcat,
             float* __restrict__ h_out, float* __restrict__ c_out)
{
    __shared__ float sh_h[EDM][104];
    __shared__ float sh_g[NG][EDM + 1];
    const int tid = threadIdx.x;
    const int b0  = blockIdx.x * EDM;
    const bool act = tid < NG;
    const int n  = act ? tid : 0;
    const int mc = n / NH, jc = n % NH;
    float bias = act ? bcat[n] : 0.f;
    float c0 = 0.f;

    W_LIST(DECL_W)
    if (act){
        W_LIST(LOADW_ENC)
        sh_h[mc][jc] = 0.f;
    }
    __syncthreads();

    for (int t = 0; t < NT; ++t){
        if (act){
            const float* xr = xp + ((size_t)b0 * NT + t) * NG + n;
            float a0 = bias + xr[0 * NT * NG];
            float a1 = bias + xr[1 * NT * NG];
            float a2 = bias + xr[2 * NT * NG];
            float a3 = bias + xr[3 * NT * NG];
            W_LIST(ESTEP)
            sh_g[n][0]=a0; sh_g[n][1]=a1; sh_g[n][2]=a2; sh_g[n][3]=a3;
        }
        __syncthreads();
        if (act){
            float ai = sh_g[jc][mc], af = sh_g[NH + jc][mc];
            float ag = sh_g[2*NH + jc][mc], ao = sh_g[3*NH + jc][mc];
            float ii = sigm(ai), ff = sigm(af), gg = tanh_fast(ag), oo = sigm(ao);
            c0 = ff * c0 + ii * gg;
            sh_h[mc][jc] = oo * tanh_fast(c0);
        }
        __syncthreads();
    }
    if (act){
        h_out[(size_t)(b0 + mc) * NH + jc] = sh_h[mc][jc];
        c_out[(size_t)(b0 + mc) * NH + jc] = c0;
    }
}

// ---------------- encoder (fallback, small ws): stream combined WencT4, 4 rows/block ----------------

__global__ __launch_bounds__(512) void enc_stream(const float* __restrict__ src,
                                                  const float4* __restrict__ WencT4,
                                                  const float* __restrict__ bcat,
                                                  float* __restrict__ h_out, float* __restrict__ c_out)
{
    __shared__ float sh_xh[4][368];   // [0,264)=x, [264,364)=h
    __shared__ float sh_g[NG][5];
    const int tid = threadIdx.x;
    const int m0  = blockIdx.x * 4;
    const bool act = tid < NG;
    const int n  = act ? tid : 0;
    const int mc = n / NH, jc = n % NH;
    float bias = act ? bcat[n] : 0.f;
    float c_reg = 0.f, h_new = 0.f;
    if (act) sh_xh[mc][NI + jc] = 0.f;
    const float* s0 = src + (size_t)m0 * NT * NI;

    for (int t = 0; t < NT; ++t){
        for (int i = tid; i < 4 * NI; i += 512){
            int r = i / NI, k = i - r * NI;
            sh_xh[r][k] = s0[(size_t)r * NT * NI + (size_t)t * NI + k];
        }
        __syncthreads();
        if (act){
            float a0 = bias, a1 = bias, a2 = bias, a3 = bias;
            #pragma unroll 7
            for (int k4 = 0; k4 < KE / 4; ++k4){
                float4 wq = WencT4[k4 * NG + n];
                float4 hq;
                hq = ((const float4*)sh_xh[0])[k4]; FMA4(a0, hq, wq)
                hq = ((const float4*)sh_xh[1])[k4]; FMA4(a1, hq, wq)
                hq = ((const float4*)sh_xh[2])[k4]; FMA4(a2, hq, wq)
                hq = ((const float4*)sh_xh[3])[k4]; FMA4(a3, hq, wq)
            }
            sh_g[n][0]=a0; sh_g[n][1]=a1; sh_g[n][2]=a2; sh_g[n][3]=a3;
        }
        __syncthreads();
        if (act){
            float ai = sh_g[jc][mc], af = sh_g[NH + jc][mc];
            float ag = sh_g[2*NH + jc][mc], ao = sh_g[3*NH + jc][mc];
            float ii = sigm(ai), ff = sigm(af), gg = tanh_fast(ag), oo = sigm(ao);
            c_reg = ff * c_reg + ii * gg;
            h_new = oo * tanh_fast(c_reg);
            sh_xh[mc][NI + jc] = h_new;
        }
        __syncthreads();
    }
    if (act){
        h_out[(size_t)(m0 + mc) * NH + jc] = h_new;
        c_out[(size_t)(m0 + mc) * NH + jc] = c_reg;
    }
}

// ---------------- decoder: C=4 columns/thread + K-split x2 ----------------
// r8 post-mortem: C=4 cut instructions but left 4.6 waves/CU -> L2-latency bound
// (VALUBusy 36%, L2 BW 28%). Split the K reduction across two wave-groups:
// kg=0 accumulates k4 in [0,13), kg=1 in [13,25); partials combined via LDS in phase 2.
// 6 waves/block x 2 blocks/CU = 12 waves, same weight traffic, half the per-thread
// serial chain. Layout (kg wave-uniform): tid 0-99 gate kg0 | 128-227 gate kg1 |
// 256-319 fc kg0 | 320-383 fc kg1 | rest idle. Gate cols n,n+100,n+200,n+300;
// fc cols o,o+64,o+128,o+192 (+256 for o<8). Activation by gate-kg0 threads;
// fc loss: wave kg combines+scores rows {2kg, 2kg+1} (splits target-load latency).

__global__ __launch_bounds__(DTH) void decoder_kernel(
    const float* __restrict__ h_enc, const float* __restrict__ c_enc,
    const float4* __restrict__ WhhT_p, const float4* __restrict__ WdecT_p,
    const float* __restrict__ b0_p,  const float* __restrict__ bdec_p,
    const float4* __restrict__ fcWT_p, const float* __restrict__ fcb_p,
    const float* __restrict__ trg,
    const float4* __restrict__ WhhT_r, const float4* __restrict__ WdecT_r,
    const float* __restrict__ b0_r,  const float* __restrict__ bdec_r,
    const float4* __restrict__ fcWT_r, const float* __restrict__ fcb_r,
    const float* __restrict__ src,
    float* __restrict__ loss)
{
    __shared__ float sh_h[DM][104];                 // 1.7 KB
    __shared__ float sh_g[2][NG][DM + 1];           // 16.0 KB gate partials
    __shared__ float sh_fp[2][64][21];              // 10.8 KB fc partials (pad 21: stride odd)
    __shared__ float sh_red[6];
    const int tid = threadIdx.x;
    const int d   = (blockIdx.x >= NDB) ? 1 : 0;
    const int m0  = (blockIdx.x - d * NDB) * DM;
    const float4* WhhT  = d ? WhhT_r  : WhhT_p;
    const float4* WdecT = d ? WdecT_r : WdecT_p;
    const float*  b0    = d ? b0_r    : b0_p;
    const float*  bdec  = d ? bdec_r  : bdec_p;
    const float4* fcWT  = d ? fcWT_r  : fcWT_p;
    const float*  fcb   = d ? fcb_r   : fcb_p;
    const float*  tgt   = d ? src     : trg;

    const bool gate0 = tid < NH;
    const bool gate1 = (tid >= 128) && (tid < 128 + NH);
    const bool gate  = gate0 || gate1;
    const bool fc0   = (tid >= 256) && (tid < 320);
    const bool fc1   = (tid >= 320);
    const bool fc    = fc0 || fc1;
    const int n  = gate1 ? (tid - 128) : tid;          // valid when gate
    const int o  = fc1 ? (tid - 320) : (tid - 256);    // valid when fc
    const bool fcx = fc && (o < 8);                    // 5th column owners
    const int kg   = (gate1 || fc1) ? 1 : 0;           // wave-uniform among active lanes
    const int KS   = kg ? 13 : 0;
    const int KEND = kg ? 25 : 13;

    float bz0=0,bz1=0,bz2=0,bz3=0, bd0=0,bd1=0,bd2=0,bd3=0;
    float fb0=0,fb1=0,fb2=0,fb3=0,fb4=0;
    if (gate0){
        bz0=b0[n];   bz1=b0[n+NH];   bz2=b0[n+2*NH];   bz3=b0[n+3*NH];
        bd0=bdec[n]; bd1=bdec[n+NH]; bd2=bdec[n+2*NH]; bd3=bdec[n+3*NH];
    } else if (fc0){
        fb0=fcb[o]; fb1=fcb[o+64]; fb2=fcb[o+128]; fb3=fcb[o+192];
        if (fcx) fb4=fcb[o+256];
    }

    float c0=0.f, c1=0.f, c2=0.f, c3=0.f;
    if (gate0){
        c0 = c_enc[(size_t)(m0+0)*NH + n];
        c1 = c_enc[(size_t)(m0+1)*NH + n];
        c2 = c_enc[(size_t)(m0+2)*NH + n];
        c3 = c_enc[(size_t)(m0+3)*NH + n];
        sh_h[0][n] = h_enc[(size_t)(m0+0)*NH + n];
        sh_h[1][n] = h_enc[(size_t)(m0+1)*NH + n];
        sh_h[2][n] = h_enc[(size_t)(m0+2)*NH + n];
        sh_h[3][n] = h_enc[(size_t)(m0+3)*NH + n];
    }
    float loss_acc = 0.f;
    __syncthreads();

    for (int k = 0; k <= NT; ++k){
        // ---- phase 1: partial matvecs ----
        if (gate && k < NT){
            const float4* WT = (k == 0) ? WhhT : WdecT;   // step 0: x=0 -> plain Whh
            float A0,A1,A2,A3,B0,B1,B2,B3,C0,C1,C2,C3,D0,D1,D2,D3;
            if (kg == 0){
                float biasA = k ? bd0 : bz0, biasB = k ? bd1 : bz1;
                float biasC = k ? bd2 : bz2, biasD = k ? bd3 : bz3;
                A0=biasA;A1=biasA;A2=biasA;A3=biasA;
                B0=biasB;B1=biasB;B2=biasB;B3=biasB;
                C0=biasC;C1=biasC;C2=biasC;C3=biasC;
                D0=biasD;D1=biasD;D2=biasD;D3=biasD;
            } else {
                A0=0;A1=0;A2=0;A3=0; B0=0;B1=0;B2=0;B3=0;
                C0=0;C1=0;C2=0;C3=0; D0=0;D1=0;D2=0;D3=0;
            }
            #pragma unroll 4
            for (int k4 = KS; k4 < KEND; ++k4){
                float4 wa = WT[k4 * NG + n];
                float4 wb = WT[k4 * NG + n + NH];
                float4 wc = WT[k4 * NG + n + 2*NH];
                float4 wd = WT[k4 * NG + n + 3*NH];
                float4 h0q = ((const float4*)sh_h[0])[k4];
                float4 h1q = ((const float4*)sh_h[1])[k4];
                float4 h2q = ((const float4*)sh_h[2])[k4];
                float4 h3q = ((const float4*)sh_h[3])[k4];
                FMA4(A0,h0q,wa) FMA4(A1,h1q,wa) FMA4(A2,h2q,wa) FMA4(A3,h3q,wa)
                FMA4(B0,h0q,wb) FMA4(B1,h1q,wb) FMA4(B2,h2q,wb) FMA4(B3,h3q,wb)
                FMA4(C0,h0q,wc) FMA4(C1,h1q,wc) FMA4(C2,h2q,wc) FMA4(C3,h3q,wc)
                FMA4(D0,h0q,wd) FMA4(D1,h1q,wd) FMA4(D2,h2q,wd) FMA4(D3,h3q,wd)
            }
            sh_g[kg][n][0]=A0;        sh_g[kg][n][1]=A1;        sh_g[kg][n][2]=A2;        sh_g[kg][n][3]=A3;
            sh_g[kg][n+NH][0]=B0;     sh_g[kg][n+NH][1]=B1;     sh_g[kg][n+NH][2]=B2;     sh_g[kg][n+NH][3]=B3;
            sh_g[kg][n+2*NH][0]=C0;   sh_g[kg][n+2*NH][1]=C1;   sh_g[kg][n+2*NH][2]=C2;   sh_g[kg][n+2*NH][3]=C3;
            sh_g[kg][n+3*NH][0]=D0;   sh_g[kg][n+3*NH][1]=D1;   sh_g[kg][n+3*NH][2]=D2;   sh_g[kg][n+3*NH][3]=D3;
        } else if (fc && k >= 1){
            float P0,P1,P2,P3,Q0,Q1,Q2,Q3,R0,R1,R2,R3,S0,S1,S2,S3,T0,T1,T2,T3;
            if (kg == 0){
                P0=fb0;P1=fb0;P2=fb0;P3=fb0; Q0=fb1;Q1=fb1;Q2=fb1;Q3=fb1;
                R0=fb2;R1=fb2;R2=fb2;R3=fb2; S0=fb3;S1=fb3;S2=fb3;S3=fb3;
                T0=fb4;T1=fb4;T2=fb4;T3=fb4;
            } else {
                P0=0;P1=0;P2=0;P3=0; Q0=0;Q1=0;Q2=0;Q3=0;
                R0=0;R1=0;R2=0;R3=0; S0=0;S1=0;S2=0;S3=0;
                T0=0;T1=0;T2=0;T3=0;
            }
            #pragma unroll 4
            for (int k4 = KS; k4 < KEND; ++k4){
                float4 wa = fcWT[k4 * NO + o];
                float4 wb = fcWT[k4 * NO + o + 64];
                float4 wc = fcWT[k4 * NO + o + 128];
                float4 wd = fcWT[k4 * NO + o + 192];
                float4 h0q = ((const float4*)sh_h[0])[k4];
                float4 h1q = ((const float4*)sh_h[1])[k4];
                float4 h2q = ((const float4*)sh_h[2])[k4];
                float4 h3q = ((const float4*)sh_h[3])[k4];
                FMA4(P0,h0q,wa) FMA4(P1,h1q,wa) FMA4(P2,h2q,wa) FMA4(P3,h3q,wa)
                FMA4(Q0,h0q,wb) FMA4(Q1,h1q,wb) FMA4(Q2,h2q,wb) FMA4(Q3,h3q,wb)
                FMA4(R0,h0q,wc) FMA4(R1,h1q,wc) FMA4(R2,h2q,wc) FMA4(R3,h3q,wc)
                FMA4(S0,h0q,wd) FMA4(S1,h1q,wd) FMA4(S2,h2q,wd) FMA4(S3,h3q,wd)
                if (fcx){
                    float4 we = fcWT[k4 * NO + o + 256];
                    FMA4(T0,h0q,we) FMA4(T1,h1q,we) FMA4(T2,h2q,we) FMA4(T3,h3q,we)
                }
            }
            float (*fp)[21] = sh_fp[kg];
            fp[o][0]=P0;  fp[o][1]=P1;  fp[o][2]=P2;  fp[o][3]=P3;
            fp[o][4]=Q0;  fp[o][5]=Q1;  fp[o][6]=Q2;  fp[o][7]=Q3;
            fp[o][8]=R0;  fp[o][9]=R1;  fp[o][10]=R2; fp[o][11]=R3;
            fp[o][12]=S0; fp[o][13]=S1; fp[o][14]=S2; fp[o][15]=S3;
            if (fcx){ fp[o][16]=T0; fp[o][17]=T1; fp[o][18]=T2; fp[o][19]=T3; }
        }
        __syncthreads();
        // ---- phase 2: activation (gate kg0) / loss combine (fc, rows 2kg..2kg+1) ----
        if (gate0 && k < NT){
            #define ACT(r, cc) { \
                float ai = sh_g[0][n][r]      + sh_g[1][n][r]; \
                float af = sh_g[0][NH+n][r]   + sh_g[1][NH+n][r]; \
                float ag = sh_g[0][2*NH+n][r] + sh_g[1][2*NH+n][r]; \
                float ao = sh_g[0][3*NH+n][r] + sh_g[1][3*NH+n][r]; \
                float ii = sigm(ai), ff = sigm(af), gg = tanh_fast(ag), oo = sigm(ao); \
                cc = ff * cc + ii * gg; \
                sh_h[r][n] = oo * tanh_fast(cc); }
            ACT(0, c0) ACT(1, c1) ACT(2, c2) ACT(3, c3)
            #undef ACT
        } else if (fc && k >= 1){
            const int ti = d ? (NT - k) : (k - 1);   // pred index k-1, reversed for recon
            const float* tg = tgt + (size_t)m0 * NT * NI + (size_t)ti * NI;
            const int r0 = 2*kg, r1 = 2*kg + 1;
            float s, df;
            #define LOSSCOL(ci, coff) \
                s = sh_fp[0][o][(ci)*4+r0] + sh_fp[1][o][(ci)*4+r0]; \
                df = s - tg[(size_t)r0*NT*NI + (coff)]; loss_acc += df*df; \
                s = sh_fp[0][o][(ci)*4+r1] + sh_fp[1][o][(ci)*4+r1]; \
                df = s - tg[(size_t)r1*NT*NI + (coff)]; loss_acc += df*df;
            LOSSCOL(0, o) LOSSCOL(1, o+64) LOSSCOL(2, o+128) LOSSCOL(3, o+192)
            if (fcx){ LOSSCOL(4, o+256) }
            #undef LOSSCOL
        }
        __syncthreads();
    }

    for (int off = 32; off > 0; off >>= 1) loss_acc += __shfl_down(loss_acc, off);
    if ((tid & 63) == 0) sh_red[tid >> 6] = loss_acc;
    __syncthreads();
    if (tid == 0){
        float s = 0.f;
        for (int w = 0; w < 6; ++w) s += sh_red[w];
        atomicAdd(&loss[d], s);
    }
}

__global__ void finalize_kernel(const float* __restrict__ loss, float* __restrict__ out){
    if (threadIdx.x == 0){
        const float inv = 1.f / 26400000.f;   // B*T*O
        out[0] = loss[1] * inv;   // reconstruct_loss
        out[1] = loss[0] * inv;   // predict_loss
    }
}

extern "C" void kernel_launch(void* const* d_in, const int* in_sizes, int n_in,
                              void* d_out, int out_size, void* d_ws, size_t ws_size,
                              hipStream_t stream)
{
    const float* src  = (const float*)d_in[0];
    const float* trg  = (const float*)d_in[1];
    const float* eWih = (const float*)d_in[2];
    const float* eWhh = (const float*)d_in[3];
    const float* ebih = (const float*)d_in[4];
    const float* ebhh = (const float*)d_in[5];
    const float* pWih = (const float*)d_in[6];
    const float* pWhh = (const float*)d_in[7];
    const float* pbih = (const float*)d_in[8];
    const float* pbhh = (const float*)d_in[9];
    const float* pfcW = (const float*)d_in[10];
    const float* pfcb = (const float*)d_in[11];
    const float* rWih = (const float*)d_in[12];
    const float* rWhh = (const float*)d_in[13];
    const float* rbih = (const float*)d_in[14];
    const float* rbhh = (const float*)d_in[15];
    const float* rfcW = (const float*)d_in[16];
    const float* rfcb = (const float*)d_in[17];

    float* w       = (float*)d_ws;
    float* WihT4e  = w;                 // 105600
    float* WencT4  = w + 105600;        // 145600 (fallback)
    float* WhhT4e  = w + 251200;        // 40000
    float* WdT_p   = w + 291200;        // 40000
    float* WdT_r   = w + 331200;        // 40000
    float* WhT_p   = w + 371200;        // 40000
    float* WhT_r   = w + 411200;        // 40000
    float* fcT_p   = w + 451200;        // 26400
    float* fcT_r   = w + 477600;        // 26400
    float* b0_p    = w + 504000;        // 400
    float* bdec_p  = w + 504400;        // 400
    float* b0_r    = w + 504800;        // 400
    float* bdec_r  = w + 505200;        // 400
    float* bcat    = w + 505600;        // 400
    float* h_enc   = w + 506000;        // 100000
    float* c_enc   = w + 606000;        // 100000
    float* loss    = w + 706000;        // 2
    float* XP      = w + 706016;        // 40,000,000 (big path only)
    const bool big = ws_size >= (size_t)(706016 + 40000000) * 4;

    const int TB = 256;
    if (big){
        prep_T4<<<(NG*NI + TB-1)/TB, TB, 0, stream>>>(eWih, WihT4e, NG, NI);
        prep_T4<<<(NG*NH + TB-1)/TB, TB, 0, stream>>>(eWhh, WhhT4e, NG, NH);
    } else {
        prep_encT<<<(NG*KE + TB-1)/TB, TB, 0, stream>>>(eWih, eWhh, WencT4);
    }
    prep_T4<<<(NG*NH + TB-1)/TB, TB, 0, stream>>>(pWhh, WhT_p, NG, NH);
    prep_T4<<<(NG*NH + TB-1)/TB, TB, 0, stream>>>(rWhh, WhT_r, NG, NH);
    prep_T4<<<(NO*NH + TB-1)/TB, TB, 0, stream>>>(pfcW, fcT_p, NO, NH);
    prep_T4<<<(NO*NH + TB-1)/TB, TB, 0, stream>>>(rfcW, fcT_r, NO, NH);
    prep_wdec<<<(NG*NH + TB-1)/TB, TB, 0, stream>>>(pWih, pWhh, pfcW, WdT_p);
    prep_wdec<<<(NG*NH + TB-1)/TB, TB, 0, stream>>>(rWih, rWhh, rfcW, WdT_r);
    prep_bias<<<4, TB, 0, stream>>>(pbih, pbhh, pWih, pfcb, rbih, rbhh, rWih, rfcb,
                                    ebih, ebhh, b0_p, bdec_p, b0_r, bdec_r, bcat, loss);

    if (big){
        xp_kernel<<<(NB*NT)/XM, 512, 0, stream>>>(src, (const float4*)WihT4e, XP);
        enc_rec<<<NB/EDM, 512, 0, stream>>>(XP, (const float4*)WhhT4e, bcat, h_enc, c_enc);
    } else {
        enc_stream<<<NB/4, 512, 0, stream>>>(src, (const float4*)WencT4, bcat, h_enc, c_enc);
    }
    decoder_kernel<<<2 * NDB, DTH, 0, stream>>>(h_enc, c_enc,
        (const float4*)WhT_p, (const float4*)WdT_p, b0_p, bdec_p, (const float4*)fcT_p, pfcb, trg,
        (const float4*)WhT_r, (const float4*)WdT_r, b0_r, bdec_r, (const float4*)fcT_r, rfcb, src,
        loss);
    finalize_kernel<<<1, 64, 0, stream>>>(loss, (float*)d_out);
}